// Round 2
// baseline (337.261 us; speedup 1.0000x reference)
//
#include <hip/hip_runtime.h>

// BertFusion: out = softmax(H @ V^T) @ V
// B=8, L=2048, V=1024, D=1024, fp32 in/out.
// 3 kernels, fp16 MFMA (16x16x32), fp32 accum. d_out doubles as scratch:
//   K1 writes fp32 scores to d_out; K2 softmaxes in place, emitting fp16 P
//   into the first 2048 B of each row's 4096 B region; K3 computes P@V and
//   overwrites each row (blocks own full rows -> no cross-block aliasing).
// d_ws is NOT used (size unknown/unverified).

typedef _Float16 half8_t __attribute__((ext_vector_type(8)));
typedef _Float16 half4_t __attribute__((ext_vector_type(4)));
typedef __fp16   fp16x2  __attribute__((ext_vector_type(2)));  // cvt_pkrtz return type
typedef float    f32x4   __attribute__((ext_vector_type(4)));

#define B_ 8
#define L_ 2048
#define V_ 1024
#define D_ 1024

__device__ inline half8_t cvt8(f32x4 a, f32x4 b) {
  fp16x2 p0 = __builtin_amdgcn_cvt_pkrtz(a[0], a[1]);
  fp16x2 p1 = __builtin_amdgcn_cvt_pkrtz(a[2], a[3]);
  fp16x2 p2 = __builtin_amdgcn_cvt_pkrtz(b[0], b[1]);
  fp16x2 p3 = __builtin_amdgcn_cvt_pkrtz(b[2], b[3]);
  half8_t r;
  r[0] = (_Float16)p0[0]; r[1] = (_Float16)p0[1];
  r[2] = (_Float16)p1[0]; r[3] = (_Float16)p1[1];
  r[4] = (_Float16)p2[0]; r[5] = (_Float16)p2[1];
  r[6] = (_Float16)p3[0]; r[7] = (_Float16)p3[1];
  return r;
}

// ---------------- K1: scores = H @ V^T (gemm_bt), fp32 out ----------------
// 128x128 tile, BK=32, 256 threads (4 waves, 2x2), dbuf LDS, 1 barrier/iter.
// LDS cell layout: cell16B[kg*128 + (m ^ (2*kg))] = row m, k = k0+kg*8..+8.
__global__ __launch_bounds__(256, 2) void k1_scores(
    const float* __restrict__ H, const float* __restrict__ Vv,
    float* __restrict__ S) {
  const int b  = blockIdx.z;
  const int m0 = blockIdx.y * 128;
  const int n0 = blockIdx.x * 128;
  const float* Hb = H  + (size_t)b * L_ * D_;
  const float* Vb = Vv + (size_t)b * V_ * D_;
  float*       Sb = S  + (size_t)b * L_ * V_;

  __shared__ __align__(16) _Float16 As[2][4096];  // 8 KB per buf
  __shared__ __align__(16) _Float16 Bs[2][4096];

  const int t    = threadIdx.x;
  const int lane = t & 63;
  const int wm   = (t >> 6) >> 1;   // wave row 0..1
  const int wn   = (t >> 6) & 1;    // wave col 0..1

  f32x4 acc[4][4];
  {
    f32x4 z = {0.f, 0.f, 0.f, 0.f};
    #pragma unroll
    for (int i = 0; i < 4; ++i)
      #pragma unroll
      for (int j = 0; j < 4; ++j) acc[i][j] = z;
  }

  const int skg = t & 3;    // staging k-group (8 floats)
  const int sm  = t >> 2;   // staging row (0..63; +64 for second pass)

  for (int kt = 0; kt < D_ / 32; ++kt) {
    const int kbase = kt * 32 + skg * 8;
    const int buf   = kt & 1;
    #pragma unroll
    for (int h = 0; h < 2; ++h) {
      const int m = sm + h * 64;
      const float* sa = Hb + (size_t)(m0 + m) * D_ + kbase;
      const float* sb = Vb + (size_t)(n0 + m) * D_ + kbase;
      f32x4 a0 = *(const f32x4*)sa;
      f32x4 a1 = *(const f32x4*)(sa + 4);
      f32x4 b0 = *(const f32x4*)sb;
      f32x4 b1 = *(const f32x4*)(sb + 4);
      const int cell = skg * 128 + (m ^ (skg * 2));  // xor-swizzle: bank-clean writes
      *(half8_t*)&As[buf][cell * 8] = cvt8(a0, a1);
      *(half8_t*)&Bs[buf][cell * 8] = cvt8(b0, b1);
    }
    __syncthreads();
    const int fkg = lane >> 4;
    const int fr  = lane & 15;
    half8_t af[4];
    #pragma unroll
    for (int mt = 0; mt < 4; ++mt) {
      const int m = wm * 64 + mt * 16 + fr;
      af[mt] = *(const half8_t*)&As[buf][(fkg * 128 + (m ^ (fkg * 2))) * 8];
    }
    #pragma unroll
    for (int nt = 0; nt < 4; ++nt) {
      const int n = wn * 64 + nt * 16 + fr;
      half8_t bf = *(const half8_t*)&Bs[buf][(fkg * 128 + (n ^ (fkg * 2))) * 8];
      #pragma unroll
      for (int mt = 0; mt < 4; ++mt)
        acc[mt][nt] = __builtin_amdgcn_mfma_f32_16x16x32_f16(af[mt], bf, acc[mt][nt], 0, 0, 0);
    }
    // dbuf: next iter stages the other buffer; buffer reuse is protected by
    // the barrier at the top of the following iteration.
  }

  // C/D layout: col = lane&15, row = (lane>>4)*4 + reg   [measured m89/m91]
  const int rq = (lane >> 4) * 4;
  #pragma unroll
  for (int mt = 0; mt < 4; ++mt)
    #pragma unroll
    for (int nt = 0; nt < 4; ++nt) {
      const int col   = n0 + wn * 64 + nt * 16 + (lane & 15);
      const int rbase = m0 + wm * 64 + mt * 16 + rq;
      #pragma unroll
      for (int r = 0; r < 4; ++r)
        Sb[(size_t)(rbase + r) * V_ + col] = acc[mt][nt][r];
    }
}

// ---------------- K2: row softmax in place, emit fp16 P ----------------
__global__ __launch_bounds__(256) void k2_softmax(float* __restrict__ S) {
  const int row = blockIdx.x;             // 0 .. B_*L_-1
  float* Sr = S + (size_t)row * V_;
  const int t = threadIdx.x;
  f32x4 s = ((const f32x4*)Sr)[t];        // cols 4t..4t+3

  float m = fmaxf(fmaxf(s[0], s[1]), fmaxf(s[2], s[3]));
  #pragma unroll
  for (int off = 1; off < 64; off <<= 1) m = fmaxf(m, __shfl_xor(m, off, 64));

  __shared__ float redm[4];
  __shared__ float reds[4];
  const int w = t >> 6;
  if ((t & 63) == 0) redm[w] = m;
  __syncthreads();
  m = fmaxf(fmaxf(redm[0], redm[1]), fmaxf(redm[2], redm[3]));

  const float e0 = __expf(s[0] - m);
  const float e1 = __expf(s[1] - m);
  const float e2 = __expf(s[2] - m);
  const float e3 = __expf(s[3] - m);
  float sum = (e0 + e1) + (e2 + e3);
  #pragma unroll
  for (int off = 1; off < 64; off <<= 1) sum += __shfl_xor(sum, off, 64);
  if ((t & 63) == 0) reds[w] = sum;
  __syncthreads();
  const float inv = 1.0f / ((reds[0] + reds[1]) + (reds[2] + reds[3]));

  // all global reads completed before the barriers above -> in-place fp16
  // write into the first 2048 B of this row's region is safe.
  half4_t p;
  p[0] = (_Float16)(e0 * inv);
  p[1] = (_Float16)(e1 * inv);
  p[2] = (_Float16)(e2 * inv);
  p[3] = (_Float16)(e3 * inv);
  *(half4_t*)((_Float16*)Sr + 4 * t) = p;
}

// ---------------- K3: out = P @ V, in place over P's rows ----------------
// 64 rows/block, 512 threads (8 waves; wave w owns d-cols [128w,128w+128)).
// V chunk (32 v x 1024 d) gather-transposed into LDS as 16B cells of
// 8 consecutive v per d. P read as A-frags straight from global fp16.
__global__ __launch_bounds__(512, 2) void k3_out(
    const float* __restrict__ Vv, float* __restrict__ O) {
  const int b  = blockIdx.y;
  const int r0 = blockIdx.x * 64;
  const float* Vb = Vv + (size_t)b * V_ * D_;
  float*       Ob = O  + (size_t)b * L_ * D_;
  const _Float16* Pb = (const _Float16*)Ob;   // row stride 2048 halves (=4096 B)

  __shared__ __align__(16) _Float16 Bs[32768];  // 64 KB: cell[kg*1024 + d]

  const int t    = threadIdx.x;
  const int lane = t & 63;
  const int w    = t >> 6;

  f32x4 acc[4][8];
  {
    f32x4 z = {0.f, 0.f, 0.f, 0.f};
    #pragma unroll
    for (int i = 0; i < 4; ++i)
      #pragma unroll
      for (int j = 0; j < 8; ++j) acc[i][j] = z;
  }

  for (int kt = 0; kt < V_ / 32; ++kt) {
    const int v0 = kt * 32;
    // stage V[v0..v0+32) x d[0..1024) -> fp16, v-contiguous cells.
    // 8 scalar loads per cell; lanes sweep d -> each load is a 256 B segment.
    #pragma unroll
    for (int i = 0; i < 8; ++i) {
      const int c  = t + i * 512;       // 0..4095
      const int kg = c >> 10;           // 0..3
      const int d  = c & 1023;
      const float* src = Vb + (size_t)(v0 + kg * 8) * D_ + d;
      f32x4 x0, x1;
      x0[0] = src[0 * D_]; x0[1] = src[1 * D_]; x0[2] = src[2 * D_]; x0[3] = src[3 * D_];
      x1[0] = src[4 * D_]; x1[1] = src[5 * D_]; x1[2] = src[6 * D_]; x1[3] = src[7 * D_];
      *(half8_t*)&Bs[(kg * 1024 + d) * 8] = cvt8(x0, x1);
    }
    __syncthreads();
    const int fkg = lane >> 4;
    const int fr  = lane & 15;
    half8_t af[4];
    #pragma unroll
    for (int mt = 0; mt < 4; ++mt)
      af[mt] = *(const half8_t*)(Pb + (size_t)(r0 + mt * 16 + fr) * 2048 + v0 + fkg * 8);
    #pragma unroll
    for (int nt = 0; nt < 8; ++nt) {
      const int d = w * 128 + nt * 16 + fr;
      half8_t bf = *(const half8_t*)&Bs[(fkg * 1024 + d) * 8];
      #pragma unroll
      for (int mt = 0; mt < 4; ++mt)
        acc[mt][nt] = __builtin_amdgcn_mfma_f32_16x16x32_f16(af[mt], bf, acc[mt][nt], 0, 0, 0);
    }
    __syncthreads();  // single-buffered Bs; also drains every wave's P loads
  }

  // Safe to overwrite: last barrier guaranteed all waves' P reads are done,
  // and this block is the only reader/writer of rows r0..r0+63.
  const int rq = (lane >> 4) * 4;
  #pragma unroll
  for (int mt = 0; mt < 4; ++mt)
    #pragma unroll
    for (int nt = 0; nt < 8; ++nt) {
      const int col   = w * 128 + nt * 16 + (lane & 15);
      const int rbase = r0 + mt * 16 + rq;
      #pragma unroll
      for (int r = 0; r < 4; ++r)
        Ob[(size_t)(rbase + r) * D_ + col] = acc[mt][nt][r];
    }
}

extern "C" void kernel_launch(void* const* d_in, const int* in_sizes, int n_in,
                              void* d_out, int out_size, void* d_ws, size_t ws_size,
                              hipStream_t stream) {
  (void)in_sizes; (void)n_in; (void)d_ws; (void)ws_size; (void)out_size;
  const float* H  = (const float*)d_in[0];   // (8, 2048, 1024)
  const float* Vv = (const float*)d_in[1];   // (8, 1024, 1024)
  float* O = (float*)d_out;                  // (8, 2048, 1024)

  k1_scores <<<dim3(V_ / 128, L_ / 128, B_), 256, 0, stream>>>(H, Vv, O);
  k2_softmax<<<dim3(B_ * L_),               256, 0, stream>>>(O);
  k3_out    <<<dim3(L_ / 64, B_),           512, 0, stream>>>(Vv, O);
}

// Round 4
// 322.777 us; speedup vs baseline: 1.0449x; 1.0449x over previous
//
#include <hip/hip_runtime.h>

// BertFusion: out = softmax(H @ V^T) @ V    B=8, L=2048, V=1024, D=1024, fp32.
//
// Fast path (needs 64 MB d_ws):
//   P0: H fp32 -> Hh fp16 (ws, 32 MB)
//   P1: V fp32 -> Vh fp16 (ws, 16 MB) + VTh fp16 transposed (ws, 16 MB)
//   G1: S = Hh @ Vh^T        (fp32 -> d_out)          [m97-structure gemm]
//   K2: softmax rows of S, emit fp16 P -> ws (REUSES Hh region; Hh is dead
//       after G1 -- stream order). Dense stride 1024.
//   G2: O = P @ VTh^T        (fp32 -> d_out)          [no aliasing: A,B in ws]
// Round-3 bug fixed here: G2 previously read P from d_out while other blocks
// wrote fp32 C into the same rows (8 blocks per row-group) -> race -> NaN.
// Slow path (ws too small): round-2 kernels (proven, 337 us).

typedef _Float16 half8_t __attribute__((ext_vector_type(8)));
typedef _Float16 half4_t __attribute__((ext_vector_type(4)));
typedef __fp16   fp16x2  __attribute__((ext_vector_type(2)));
typedef float    f32x4   __attribute__((ext_vector_type(4)));

#define B_ 8
#define L_ 2048
#define V_ 1024
#define D_ 1024

__device__ __forceinline__ half8_t cvt8(f32x4 a, f32x4 b) {
  union { half8_t h; fp16x2 p[4]; } u;
  u.p[0] = __builtin_amdgcn_cvt_pkrtz(a[0], a[1]);
  u.p[1] = __builtin_amdgcn_cvt_pkrtz(a[2], a[3]);
  u.p[2] = __builtin_amdgcn_cvt_pkrtz(b[0], b[1]);
  u.p[3] = __builtin_amdgcn_cvt_pkrtz(b[2], b[3]);
  return u.h;
}
__device__ __forceinline__ half4_t cvt4(f32x4 a) {
  union { half4_t h; fp16x2 p[2]; } u;
  u.p[0] = __builtin_amdgcn_cvt_pkrtz(a[0], a[1]);
  u.p[1] = __builtin_amdgcn_cvt_pkrtz(a[2], a[3]);
  return u.h;
}

__device__ __forceinline__ void gload_lds16(const _Float16* g, _Float16* l) {
  __builtin_amdgcn_global_load_lds(
      (const __attribute__((address_space(1))) unsigned int*)(g),
      (__attribute__((address_space(3))) unsigned int*)(l), 16, 0, 0);
}

// ---------------- P0: H fp32 -> Hh fp16 ----------------
__global__ __launch_bounds__(256) void p0_hconv(const float* __restrict__ H,
                                                _Float16* __restrict__ Hh) {
  const size_t i = ((size_t)blockIdx.x * 256 + threadIdx.x) * 8;  // 8 el/thread
  f32x4 a = *(const f32x4*)(H + i);
  f32x4 b = *(const f32x4*)(H + i + 4);
  *(half8_t*)(Hh + i) = cvt8(a, b);
}

// ---------------- P1: V fp32 -> Vh fp16 + VTh fp16 (transposed) ----------
// 64x64 tiles. Lt[d][v] padded to 80 halves/row (160 B, 16-aligned).
__global__ __launch_bounds__(256) void p1_vconv(const float* __restrict__ V,
                                                _Float16* __restrict__ Vh,
                                                _Float16* __restrict__ VTh) {
  const int b  = blockIdx.z;
  const int d0 = blockIdx.x * 64;
  const int v0 = blockIdx.y * 64;
  const float* Vb = V + (size_t)b * V_ * D_;
  __shared__ __align__(16) _Float16 Lt[64 * 80];
  const int t   = threadIdx.x;
  const int dc4 = (t & 15) * 4;
  #pragma unroll
  for (int it = 0; it < 4; ++it) {
    const int vr = (t >> 4) + it * 16;
    f32x4 x = *(const f32x4*)(Vb + (size_t)(v0 + vr) * D_ + d0 + dc4);
    half4_t h = cvt4(x);
    *(half4_t*)(Vh + (size_t)b * V_ * D_ + (size_t)(v0 + vr) * D_ + d0 + dc4) = h;
    #pragma unroll
    for (int j = 0; j < 4; ++j) Lt[(dc4 + j) * 80 + vr] = h[j];
  }
  __syncthreads();
  #pragma unroll
  for (int it = 0; it < 2; ++it) {
    const int dr = (t >> 3) + it * 32;
    const int vc = (t & 7) * 8;
    half8_t y = *(const half8_t*)&Lt[dr * 80 + vc];
    *(half8_t*)(VTh + (size_t)b * D_ * V_ + (size_t)(d0 + dr) * V_ + v0 + vc) = y;
  }
}

// ---------------- G: fp16 gemm_bt, m97 structure ----------------
// C[m][n] = sum_k A[m][k] * B[n][k].  K=1024, N=1024, C row stride 1024.
// 128x128 tile, BK=32, 256 thr (4 waves 2x2), dbuf LDS, global_load_lds(16),
// prefetch kt+1 issued after barrier, before compute kt.
// LDS layout: cell16B[kg*128 + row]; staging is lane-contiguous within each
// wave (global_load_lds requirement: uniform base + lane*16).
__global__ __launch_bounds__(256, 2) void gemm_bt16(
    const _Float16* __restrict__ A, const _Float16* __restrict__ B,
    float* __restrict__ C, long aStride, long aBatch, long bBatch, long cBatch) {
  const int bz = blockIdx.z;
  const int m0 = blockIdx.y * 128;
  const int n0 = blockIdx.x * 128;
  const _Float16* Ab = A + (size_t)bz * aBatch;
  const _Float16* Bb = B + (size_t)bz * bBatch;
  float*          Cb = C + (size_t)bz * cBatch;

  __shared__ __align__(16) _Float16 As[2][4096];
  __shared__ __align__(16) _Float16 Bs[2][4096];

  const int t    = threadIdx.x;
  const int lane = t & 63;
  const int wm   = (t >> 6) >> 1;
  const int wn   = (t >> 6) & 1;

  f32x4 acc[4][4];
  {
    f32x4 z = {0.f, 0.f, 0.f, 0.f};
    #pragma unroll
    for (int i = 0; i < 4; ++i)
      #pragma unroll
      for (int j = 0; j < 4; ++j) acc[i][j] = z;
  }

  const int r0c = t & 127;         // staging row
  const int kg0 = t >> 7;          // 0..1 ; h=1 adds 2

  #define STAGE(ktv)                                                          \
    {                                                                         \
      const int bufS = (ktv) & 1;                                             \
      _Pragma("unroll")                                                       \
      for (int h = 0; h < 2; ++h) {                                           \
        const int kg  = kg0 + 2 * h;                                          \
        const int ci  = kg * 128 + r0c;                                       \
        gload_lds16(Ab + (size_t)(m0 + r0c) * aStride + (ktv) * 32 + kg * 8,  \
                    &As[bufS][ci * 8]);                                       \
        gload_lds16(Bb + (size_t)(n0 + r0c) * 1024    + (ktv) * 32 + kg * 8,  \
                    &Bs[bufS][ci * 8]);                                       \
      }                                                                       \
    }

  STAGE(0)
  for (int kt = 0; kt < 32; ++kt) {
    __syncthreads();                 // drains this wave's stage(kt) (vmcnt 0)
    if (kt < 31) STAGE(kt + 1)       // async into other buffer, overlaps MFMA
    const int buf = kt & 1;
    const int fkg = lane >> 4;
    const int fr  = lane & 15;
    half8_t af[4];
    #pragma unroll
    for (int mt = 0; mt < 4; ++mt)
      af[mt] = *(const half8_t*)&As[buf][(fkg * 128 + wm * 64 + mt * 16 + fr) * 8];
    #pragma unroll
    for (int nt = 0; nt < 4; ++nt) {
      half8_t bf = *(const half8_t*)&Bs[buf][(fkg * 128 + wn * 64 + nt * 16 + fr) * 8];
      #pragma unroll
      for (int mt = 0; mt < 4; ++mt)
        acc[mt][nt] = __builtin_amdgcn_mfma_f32_16x16x32_f16(af[mt], bf, acc[mt][nt], 0, 0, 0);
    }
  }
  #undef STAGE

  // C/D layout: col = lane&15, row = (lane>>4)*4 + reg   [m89/m91]
  const int rq = (lane >> 4) * 4;
  #pragma unroll
  for (int mt = 0; mt < 4; ++mt)
    #pragma unroll
    for (int nt = 0; nt < 4; ++nt) {
      const int col   = n0 + wn * 64 + nt * 16 + (lane & 15);
      const int rbase = m0 + wm * 64 + mt * 16 + rq;
      #pragma unroll
      for (int r = 0; r < 4; ++r)
        Cb[(size_t)(rbase + r) * 1024 + col] = acc[mt][nt][r];
    }
}

// ---------------- K2: row softmax, S (fp32, d_out) -> P (fp16, ws) --------
__global__ __launch_bounds__(256) void k2_softmax(const float* __restrict__ S,
                                                  _Float16* __restrict__ P) {
  const int row = blockIdx.x;
  const float* Sr = S + (size_t)row * V_;
  const int t = threadIdx.x;
  f32x4 s = ((const f32x4*)Sr)[t];

  float m = fmaxf(fmaxf(s[0], s[1]), fmaxf(s[2], s[3]));
  #pragma unroll
  for (int off = 1; off < 64; off <<= 1) m = fmaxf(m, __shfl_xor(m, off, 64));

  __shared__ float redm[4];
  __shared__ float reds[4];
  const int w = t >> 6;
  if ((t & 63) == 0) redm[w] = m;
  __syncthreads();
  m = fmaxf(fmaxf(redm[0], redm[1]), fmaxf(redm[2], redm[3]));

  const float e0 = __expf(s[0] - m);
  const float e1 = __expf(s[1] - m);
  const float e2 = __expf(s[2] - m);
  const float e3 = __expf(s[3] - m);
  float sum = (e0 + e1) + (e2 + e3);
  #pragma unroll
  for (int off = 1; off < 64; off <<= 1) sum += __shfl_xor(sum, off, 64);
  if ((t & 63) == 0) reds[w] = sum;
  __syncthreads();
  const float inv = 1.0f / ((reds[0] + reds[1]) + (reds[2] + reds[3]));

  half4_t p;
  p[0] = (_Float16)(e0 * inv);
  p[1] = (_Float16)(e1 * inv);
  p[2] = (_Float16)(e2 * inv);
  p[3] = (_Float16)(e3 * inv);
  *(half4_t*)(P + (size_t)row * V_ + 4 * t) = p;
}

// ================= slow fallback (round-2, proven) =================
__global__ __launch_bounds__(256, 2) void k1_slow(
    const float* __restrict__ H, const float* __restrict__ Vv, float* __restrict__ S) {
  const int b  = blockIdx.z;
  const int m0 = blockIdx.y * 128;
  const int n0 = blockIdx.x * 128;
  const float* Hb = H  + (size_t)b * L_ * D_;
  const float* Vb = Vv + (size_t)b * V_ * D_;
  float*       Sb = S  + (size_t)b * L_ * V_;
  __shared__ __align__(16) _Float16 As[2][4096];
  __shared__ __align__(16) _Float16 Bs[2][4096];
  const int t = threadIdx.x, lane = t & 63, wm = (t >> 6) >> 1, wn = (t >> 6) & 1;
  f32x4 acc[4][4];
  { f32x4 z = {0,0,0,0};
    #pragma unroll
    for (int i = 0; i < 4; ++i)
      #pragma unroll
      for (int j = 0; j < 4; ++j) acc[i][j] = z; }
  const int skg = t & 3, sm = t >> 2;
  for (int kt = 0; kt < 32; ++kt) {
    const int kbase = kt * 32 + skg * 8, buf = kt & 1;
    #pragma unroll
    for (int h = 0; h < 2; ++h) {
      const int m = sm + h * 64;
      const float* sa = Hb + (size_t)(m0 + m) * D_ + kbase;
      const float* sb = Vb + (size_t)(n0 + m) * D_ + kbase;
      const int cell = skg * 128 + (m ^ (skg * 2));
      *(half8_t*)&As[buf][cell * 8] = cvt8(*(const f32x4*)sa, *(const f32x4*)(sa + 4));
      *(half8_t*)&Bs[buf][cell * 8] = cvt8(*(const f32x4*)sb, *(const f32x4*)(sb + 4));
    }
    __syncthreads();
    const int fkg = lane >> 4, fr = lane & 15;
    half8_t af[4];
    #pragma unroll
    for (int mt = 0; mt < 4; ++mt)
      af[mt] = *(const half8_t*)&As[buf][(fkg * 128 + ((wm * 64 + mt * 16 + fr) ^ (fkg * 2))) * 8];
    #pragma unroll
    for (int nt = 0; nt < 4; ++nt) {
      half8_t bf = *(const half8_t*)&Bs[buf][(fkg * 128 + ((wn * 64 + nt * 16 + fr) ^ (fkg * 2))) * 8];
      #pragma unroll
      for (int mt = 0; mt < 4; ++mt)
        acc[mt][nt] = __builtin_amdgcn_mfma_f32_16x16x32_f16(af[mt], bf, acc[mt][nt], 0, 0, 0);
    }
  }
  const int rq = (lane >> 4) * 4;
  #pragma unroll
  for (int mt = 0; mt < 4; ++mt)
    #pragma unroll
    for (int nt = 0; nt < 4; ++nt) {
      const int col = n0 + wn * 64 + nt * 16 + (lane & 15);
      const int rb  = m0 + wm * 64 + mt * 16 + rq;
      #pragma unroll
      for (int r = 0; r < 4; ++r) Sb[(size_t)(rb + r) * V_ + col] = acc[mt][nt][r];
    }
}

__global__ __launch_bounds__(256) void k2_slow(float* __restrict__ S) {
  const int row = blockIdx.x;
  float* Sr = S + (size_t)row * V_;
  const int t = threadIdx.x;
  f32x4 s = ((const f32x4*)Sr)[t];
  float m = fmaxf(fmaxf(s[0], s[1]), fmaxf(s[2], s[3]));
  #pragma unroll
  for (int off = 1; off < 64; off <<= 1) m = fmaxf(m, __shfl_xor(m, off, 64));
  __shared__ float redm[4];
  __shared__ float reds[4];
  const int w = t >> 6;
  if ((t & 63) == 0) redm[w] = m;
  __syncthreads();
  m = fmaxf(fmaxf(redm[0], redm[1]), fmaxf(redm[2], redm[3]));
  const float e0 = __expf(s[0] - m), e1 = __expf(s[1] - m);
  const float e2 = __expf(s[2] - m), e3 = __expf(s[3] - m);
  float sum = (e0 + e1) + (e2 + e3);
  #pragma unroll
  for (int off = 1; off < 64; off <<= 1) sum += __shfl_xor(sum, off, 64);
  if ((t & 63) == 0) reds[w] = sum;
  __syncthreads();
  const float inv = 1.0f / ((reds[0] + reds[1]) + (reds[2] + reds[3]));
  half4_t p;
  p[0] = (_Float16)(e0 * inv); p[1] = (_Float16)(e1 * inv);
  p[2] = (_Float16)(e2 * inv); p[3] = (_Float16)(e3 * inv);
  *(half4_t*)((_Float16*)Sr + 4 * t) = p;
}

__global__ __launch_bounds__(512, 2) void k3_slow(
    const float* __restrict__ Vv, float* __restrict__ O) {
  const int b = blockIdx.y, r0 = blockIdx.x * 64;
  const float* Vb = Vv + (size_t)b * V_ * D_;
  float*       Ob = O  + (size_t)b * L_ * D_;
  const _Float16* Pb = (const _Float16*)Ob;
  __shared__ __align__(16) _Float16 Bs[32768];
  const int t = threadIdx.x, lane = t & 63, w = t >> 6;
  f32x4 acc[4][8];
  { f32x4 z = {0,0,0,0};
    #pragma unroll
    for (int i = 0; i < 4; ++i)
      #pragma unroll
      for (int j = 0; j < 8; ++j) acc[i][j] = z; }
  for (int kt = 0; kt < 32; ++kt) {
    const int v0 = kt * 32;
    #pragma unroll
    for (int i = 0; i < 8; ++i) {
      const int c = t + i * 512, kg = c >> 10, d = c & 1023;
      const float* src = Vb + (size_t)(v0 + kg * 8) * D_ + d;
      f32x4 x0, x1;
      x0[0] = src[0*D_]; x0[1] = src[1*D_]; x0[2] = src[2*D_]; x0[3] = src[3*D_];
      x1[0] = src[4*D_]; x1[1] = src[5*D_]; x1[2] = src[6*D_]; x1[3] = src[7*D_];
      *(half8_t*)&Bs[(kg * 1024 + d) * 8] = cvt8(x0, x1);
    }
    __syncthreads();
    const int fkg = lane >> 4, fr = lane & 15;
    half8_t af[4];
    #pragma unroll
    for (int mt = 0; mt < 4; ++mt)
      af[mt] = *(const half8_t*)(Pb + (size_t)(r0 + mt * 16 + fr) * 2048 + v0 + fkg * 8);
    #pragma unroll
    for (int nt = 0; nt < 8; ++nt) {
      half8_t bf = *(const half8_t*)&Bs[(fkg * 1024 + w * 128 + nt * 16 + fr) * 8];
      #pragma unroll
      for (int mt = 0; mt < 4; ++mt)
        acc[mt][nt] = __builtin_amdgcn_mfma_f32_16x16x32_f16(af[mt], bf, acc[mt][nt], 0, 0, 0);
    }
    __syncthreads();
  }
  const int rq = (lane >> 4) * 4;
  #pragma unroll
  for (int mt = 0; mt < 4; ++mt)
    #pragma unroll
    for (int nt = 0; nt < 8; ++nt) {
      const int col = w * 128 + nt * 16 + (lane & 15);
      const int rb  = r0 + mt * 16 + rq;
      #pragma unroll
      for (int r = 0; r < 4; ++r) Ob[(size_t)(rb + r) * D_ + col] = acc[mt][nt][r];
    }
}

extern "C" void kernel_launch(void* const* d_in, const int* in_sizes, int n_in,
                              void* d_out, int out_size, void* d_ws, size_t ws_size,
                              hipStream_t stream) {
  (void)in_sizes; (void)n_in; (void)out_size;
  const float* H  = (const float*)d_in[0];   // (8, 2048, 1024)
  const float* Vv = (const float*)d_in[1];   // (8, 1024, 1024)
  float* O = (float*)d_out;                  // (8, 2048, 1024)

  const size_t need = (size_t)64 * 1024 * 1024;  // Hh/P 32M + Vh 16M + VTh 16M
  if (ws_size >= need && d_ws != nullptr) {
    _Float16* Hh  = (_Float16*)d_ws;            // 32 MB; becomes P after G1
    _Float16* Vh  = Hh + (size_t)B_ * L_ * D_;  // 16 MB
    _Float16* VTh = Vh + (size_t)B_ * V_ * D_;  // 16 MB
    _Float16* P   = Hh;                         // reuse (Hh dead after G1)

    p0_hconv<<<dim3((B_ * L_ * D_) / (256 * 8)), 256, 0, stream>>>(H, Hh);
    p1_vconv<<<dim3(D_ / 64, V_ / 64, B_), 256, 0, stream>>>(Vv, Vh, VTh);
    // S = Hh @ Vh^T  -> d_out
    gemm_bt16<<<dim3(V_ / 128, L_ / 128, B_), 256, 0, stream>>>(
        Hh, Vh, O, (long)D_, (long)L_ * D_, (long)V_ * D_, (long)L_ * V_);
    // P = softmax(S) -> ws (fp16, dense)
    k2_softmax<<<dim3(B_ * L_), 256, 0, stream>>>(O, P);
    // O = P @ VTh^T  -> d_out (A,B both in ws: no aliasing with C)
    gemm_bt16<<<dim3(D_ / 128, L_ / 128, B_), 256, 0, stream>>>(
        P, VTh, O, (long)V_, (long)L_ * V_, (long)D_ * V_, (long)L_ * D_);
  } else {
    k1_slow<<<dim3(V_ / 128, L_ / 128, B_), 256, 0, stream>>>(H, Vv, O);
    k2_slow<<<dim3(B_ * L_), 256, 0, stream>>>(O);
    k3_slow<<<dim3(L_ / 64, B_), 512, 0, stream>>>(Vv, O);
  }
}

// Round 5
// 321.491 us; speedup vs baseline: 1.0491x; 1.0040x over previous
//
#include <hip/hip_runtime.h>

// BertFusion: out = softmax(H @ V^T) @ V    B=8, L=2048, V=1024, D=1024, fp32.
//
// Fast path (needs 64 MB d_ws):
//   P0: H fp32 -> Hh fp16 (ws, 32 MB)
//   P1: V fp32 -> Vh fp16 (ws, 16 MB) + VTh fp16 transposed (ws, 16 MB)
//   G1: S = Hh @ Vh^T        (fp32 -> d_out)   [m97-structure gemm, 4 blk/CU]
//   K2: softmax rows of S -> fp16 P in ws (reuses Hh; dead after G1).
//       One wave per row, no barriers.
//   G2: O = P @ VTh^T        (fp32 -> d_out)   [A,B in ws: no aliasing]
// Slow path (ws too small): round-2 kernels (proven, 337 us).

typedef _Float16 half8_t __attribute__((ext_vector_type(8)));
typedef _Float16 half4_t __attribute__((ext_vector_type(4)));
typedef __fp16   fp16x2  __attribute__((ext_vector_type(2)));
typedef float    f32x4   __attribute__((ext_vector_type(4)));

#define B_ 8
#define L_ 2048
#define V_ 1024
#define D_ 1024

__device__ __forceinline__ half8_t cvt8(f32x4 a, f32x4 b) {
  union { half8_t h; fp16x2 p[4]; } u;
  u.p[0] = __builtin_amdgcn_cvt_pkrtz(a[0], a[1]);
  u.p[1] = __builtin_amdgcn_cvt_pkrtz(a[2], a[3]);
  u.p[2] = __builtin_amdgcn_cvt_pkrtz(b[0], b[1]);
  u.p[3] = __builtin_amdgcn_cvt_pkrtz(b[2], b[3]);
  return u.h;
}
__device__ __forceinline__ half4_t cvt4(f32x4 a) {
  union { half4_t h; fp16x2 p[2]; } u;
  u.p[0] = __builtin_amdgcn_cvt_pkrtz(a[0], a[1]);
  u.p[1] = __builtin_amdgcn_cvt_pkrtz(a[2], a[3]);
  return u.h;
}

__device__ __forceinline__ void gload_lds16(const _Float16* g, _Float16* l) {
  __builtin_amdgcn_global_load_lds(
      (const __attribute__((address_space(1))) unsigned int*)(g),
      (__attribute__((address_space(3))) unsigned int*)(l), 16, 0, 0);
}

// ---------------- P0: H fp32 -> Hh fp16 ----------------
__global__ __launch_bounds__(256) void p0_hconv(const float* __restrict__ H,
                                                _Float16* __restrict__ Hh) {
  const size_t i = ((size_t)blockIdx.x * 256 + threadIdx.x) * 8;  // 8 el/thread
  f32x4 a = *(const f32x4*)(H + i);
  f32x4 b = *(const f32x4*)(H + i + 4);
  *(half8_t*)(Hh + i) = cvt8(a, b);
}

// ---------------- P1: V fp32 -> Vh fp16 + VTh fp16 (transposed) ----------
// 64x64 tiles. Lt[d][v] padded to 80 halves/row (160 B, 16-aligned).
__global__ __launch_bounds__(256) void p1_vconv(const float* __restrict__ V,
                                                _Float16* __restrict__ Vh,
                                                _Float16* __restrict__ VTh) {
  const int b  = blockIdx.z;
  const int d0 = blockIdx.x * 64;
  const int v0 = blockIdx.y * 64;
  const float* Vb = V + (size_t)b * V_ * D_;
  __shared__ __align__(16) _Float16 Lt[64 * 80];
  const int t   = threadIdx.x;
  const int dc4 = (t & 15) * 4;
  #pragma unroll
  for (int it = 0; it < 4; ++it) {
    const int vr = (t >> 4) + it * 16;
    f32x4 x = *(const f32x4*)(Vb + (size_t)(v0 + vr) * D_ + d0 + dc4);
    half4_t h = cvt4(x);
    *(half4_t*)(Vh + (size_t)b * V_ * D_ + (size_t)(v0 + vr) * D_ + d0 + dc4) = h;
    #pragma unroll
    for (int j = 0; j < 4; ++j) Lt[(dc4 + j) * 80 + vr] = h[j];
  }
  __syncthreads();
  #pragma unroll
  for (int it = 0; it < 2; ++it) {
    const int dr = (t >> 3) + it * 32;
    const int vc = (t & 7) * 8;
    half8_t y = *(const half8_t*)&Lt[dr * 80 + vc];
    *(half8_t*)(VTh + (size_t)b * D_ * V_ + (size_t)(d0 + dr) * V_ + v0 + vc) = y;
  }
}

// ---------------- G: fp16 gemm_bt, m97 structure, 4 blocks/CU -------------
// C[m][n] = sum_k A[m][k] * B[n][k].  K=1024, N=1024, C row stride 1024.
// 128x128 tile, BK=32, 256 thr (4 waves 2x2), dbuf LDS, global_load_lds(16),
// prefetch kt+1 issued after barrier, before compute kt.
// launch_bounds(256,4): 4 waves/EU -> 4 blocks/CU (LDS 4x32=128<=160 KB,
// regs ~48 VGPR + 64 AGPR = 112 <= 128). Small-K shape is barrier-stall
// bound at 2 blk/CU (MfmaUtil 14.5%, VALUBusy 8.3% in r4) -> cross-block
// overlap is the available lever.
__global__ __launch_bounds__(256, 4) void gemm_bt16(
    const _Float16* __restrict__ A, const _Float16* __restrict__ B,
    float* __restrict__ C, long aStride, long aBatch, long bBatch, long cBatch) {
  const int bz = blockIdx.z;
  const int m0 = blockIdx.y * 128;
  const int n0 = blockIdx.x * 128;
  const _Float16* Ab = A + (size_t)bz * aBatch;
  const _Float16* Bb = B + (size_t)bz * bBatch;
  float*          Cb = C + (size_t)bz * cBatch;

  __shared__ __align__(16) _Float16 As[2][4096];
  __shared__ __align__(16) _Float16 Bs[2][4096];

  const int t    = threadIdx.x;
  const int lane = t & 63;
  const int wm   = (t >> 6) >> 1;
  const int wn   = (t >> 6) & 1;

  f32x4 acc[4][4];
  {
    f32x4 z = {0.f, 0.f, 0.f, 0.f};
    #pragma unroll
    for (int i = 0; i < 4; ++i)
      #pragma unroll
      for (int j = 0; j < 4; ++j) acc[i][j] = z;
  }

  const int r0c = t & 127;         // staging row
  const int kg0 = t >> 7;          // 0..1 ; h=1 adds 2

  #define STAGE(ktv)                                                          \
    {                                                                         \
      const int bufS = (ktv) & 1;                                             \
      _Pragma("unroll")                                                       \
      for (int h = 0; h < 2; ++h) {                                           \
        const int kg  = kg0 + 2 * h;                                          \
        const int ci  = kg * 128 + r0c;                                       \
        gload_lds16(Ab + (size_t)(m0 + r0c) * aStride + (ktv) * 32 + kg * 8,  \
                    &As[bufS][ci * 8]);                                       \
        gload_lds16(Bb + (size_t)(n0 + r0c) * 1024    + (ktv) * 32 + kg * 8,  \
                    &Bs[bufS][ci * 8]);                                       \
      }                                                                       \
    }

  STAGE(0)
  for (int kt = 0; kt < 32; ++kt) {
    __syncthreads();                 // drains stage(kt) (vmcnt 0 at barrier)
    if (kt < 31) STAGE(kt + 1)       // async into other buffer, overlaps MFMA
    const int buf = kt & 1;
    const int fkg = lane >> 4;
    const int fr  = lane & 15;
    half8_t af[4];
    #pragma unroll
    for (int mt = 0; mt < 4; ++mt)
      af[mt] = *(const half8_t*)&As[buf][(fkg * 128 + wm * 64 + mt * 16 + fr) * 8];
    #pragma unroll
    for (int nt = 0; nt < 4; ++nt) {
      half8_t bf = *(const half8_t*)&Bs[buf][(fkg * 128 + wn * 64 + nt * 16 + fr) * 8];
      #pragma unroll
      for (int mt = 0; mt < 4; ++mt)
        acc[mt][nt] = __builtin_amdgcn_mfma_f32_16x16x32_f16(af[mt], bf, acc[mt][nt], 0, 0, 0);
    }
  }
  #undef STAGE

  // C/D layout: col = lane&15, row = (lane>>4)*4 + reg   [m89/m91]
  const int rq = (lane >> 4) * 4;
  #pragma unroll
  for (int mt = 0; mt < 4; ++mt)
    #pragma unroll
    for (int nt = 0; nt < 4; ++nt) {
      const int col   = n0 + wn * 64 + nt * 16 + (lane & 15);
      const int rbase = m0 + wm * 64 + mt * 16 + rq;
      #pragma unroll
      for (int r = 0; r < 4; ++r)
        Cb[(size_t)(rbase + r) * 1024 + col] = acc[mt][nt][r];
    }
}

// ---------------- K2: softmax, one wave per row, no barriers --------------
// S (fp32, d_out) -> P (fp16, ws). Lane holds 16 cols as 4x f32x4 strided
// by 256 floats -> every load/store is wave-contiguous.
__global__ __launch_bounds__(256) void k2_softmax(const float* __restrict__ S,
                                                  _Float16* __restrict__ P) {
  const int t    = threadIdx.x;
  const int lane = t & 63;
  const int row  = blockIdx.x * 4 + (t >> 6);
  const float* Sr = S + (size_t)row * V_;

  f32x4 s[4];
  #pragma unroll
  for (int j = 0; j < 4; ++j) s[j] = *(const f32x4*)(Sr + (lane + 64 * j) * 4);

  float m = -1e30f;
  #pragma unroll
  for (int j = 0; j < 4; ++j)
    m = fmaxf(m, fmaxf(fmaxf(s[j][0], s[j][1]), fmaxf(s[j][2], s[j][3])));
  #pragma unroll
  for (int off = 1; off < 64; off <<= 1) m = fmaxf(m, __shfl_xor(m, off, 64));

  float sum = 0.f;
  #pragma unroll
  for (int j = 0; j < 4; ++j) {
    s[j][0] = __expf(s[j][0] - m); s[j][1] = __expf(s[j][1] - m);
    s[j][2] = __expf(s[j][2] - m); s[j][3] = __expf(s[j][3] - m);
    sum += (s[j][0] + s[j][1]) + (s[j][2] + s[j][3]);
  }
  #pragma unroll
  for (int off = 1; off < 64; off <<= 1) sum += __shfl_xor(sum, off, 64);
  const float inv = 1.0f / sum;

  _Float16* Pr = P + (size_t)row * V_;
  #pragma unroll
  for (int j = 0; j < 4; ++j) {
    f32x4 e = {s[j][0] * inv, s[j][1] * inv, s[j][2] * inv, s[j][3] * inv};
    *(half4_t*)(Pr + (lane + 64 * j) * 4) = cvt4(e);
  }
}

// ================= slow fallback (round-2, proven) =================
__global__ __launch_bounds__(256, 2) void k1_slow(
    const float* __restrict__ H, const float* __restrict__ Vv, float* __restrict__ S) {
  const int b  = blockIdx.z;
  const int m0 = blockIdx.y * 128;
  const int n0 = blockIdx.x * 128;
  const float* Hb = H  + (size_t)b * L_ * D_;
  const float* Vb = Vv + (size_t)b * V_ * D_;
  float*       Sb = S  + (size_t)b * L_ * V_;
  __shared__ __align__(16) _Float16 As[2][4096];
  __shared__ __align__(16) _Float16 Bs[2][4096];
  const int t = threadIdx.x, lane = t & 63, wm = (t >> 6) >> 1, wn = (t >> 6) & 1;
  f32x4 acc[4][4];
  { f32x4 z = {0,0,0,0};
    #pragma unroll
    for (int i = 0; i < 4; ++i)
      #pragma unroll
      for (int j = 0; j < 4; ++j) acc[i][j] = z; }
  const int skg = t & 3, sm = t >> 2;
  for (int kt = 0; kt < 32; ++kt) {
    const int kbase = kt * 32 + skg * 8, buf = kt & 1;
    #pragma unroll
    for (int h = 0; h < 2; ++h) {
      const int m = sm + h * 64;
      const float* sa = Hb + (size_t)(m0 + m) * D_ + kbase;
      const float* sb = Vb + (size_t)(n0 + m) * D_ + kbase;
      const int cell = skg * 128 + (m ^ (skg * 2));
      *(half8_t*)&As[buf][cell * 8] = cvt8(*(const f32x4*)sa, *(const f32x4*)(sa + 4));
      *(half8_t*)&Bs[buf][cell * 8] = cvt8(*(const f32x4*)sb, *(const f32x4*)(sb + 4));
    }
    __syncthreads();
    const int fkg = lane >> 4, fr = lane & 15;
    half8_t af[4];
    #pragma unroll
    for (int mt = 0; mt < 4; ++mt)
      af[mt] = *(const half8_t*)&As[buf][(fkg * 128 + ((wm * 64 + mt * 16 + fr) ^ (fkg * 2))) * 8];
    #pragma unroll
    for (int nt = 0; nt < 4; ++nt) {
      half8_t bf = *(const half8_t*)&Bs[buf][(fkg * 128 + ((wn * 64 + nt * 16 + fr) ^ (fkg * 2))) * 8];
      #pragma unroll
      for (int mt = 0; mt < 4; ++mt)
        acc[mt][nt] = __builtin_amdgcn_mfma_f32_16x16x32_f16(af[mt], bf, acc[mt][nt], 0, 0, 0);
    }
  }
  const int rq = (lane >> 4) * 4;
  #pragma unroll
  for (int mt = 0; mt < 4; ++mt)
    #pragma unroll
    for (int nt = 0; nt < 4; ++nt) {
      const int col = n0 + wn * 64 + nt * 16 + (lane & 15);
      const int rb  = m0 + wm * 64 + mt * 16 + rq;
      #pragma unroll
      for (int r = 0; r < 4; ++r) Sb[(size_t)(rb + r) * V_ + col] = acc[mt][nt][r];
    }
}

__global__ __launch_bounds__(256) void k2_slow(float* __restrict__ S) {
  const int row = blockIdx.x;
  float* Sr = S + (size_t)row * V_;
  const int t = threadIdx.x;
  f32x4 s = ((const f32x4*)Sr)[t];
  float m = fmaxf(fmaxf(s[0], s[1]), fmaxf(s[2], s[3]));
  #pragma unroll
  for (int off = 1; off < 64; off <<= 1) m = fmaxf(m, __shfl_xor(m, off, 64));
  __shared__ float redm[4];
  __shared__ float reds[4];
  const int w = t >> 6;
  if ((t & 63) == 0) redm[w] = m;
  __syncthreads();
  m = fmaxf(fmaxf(redm[0], redm[1]), fmaxf(redm[2], redm[3]));
  const float e0 = __expf(s[0] - m), e1 = __expf(s[1] - m);
  const float e2 = __expf(s[2] - m), e3 = __expf(s[3] - m);
  float sum = (e0 + e1) + (e2 + e3);
  #pragma unroll
  for (int off = 1; off < 64; off <<= 1) sum += __shfl_xor(sum, off, 64);
  if ((t & 63) == 0) reds[w] = sum;
  __syncthreads();
  const float inv = 1.0f / ((reds[0] + reds[1]) + (reds[2] + reds[3]));
  half4_t p;
  p[0] = (_Float16)(e0 * inv); p[1] = (_Float16)(e1 * inv);
  p[2] = (_Float16)(e2 * inv); p[3] = (_Float16)(e3 * inv);
  *(half4_t*)((_Float16*)Sr + 4 * t) = p;
}

__global__ __launch_bounds__(512, 2) void k3_slow(
    const float* __restrict__ Vv, float* __restrict__ O) {
  const int b = blockIdx.y, r0 = blockIdx.x * 64;
  const float* Vb = Vv + (size_t)b * V_ * D_;
  float*       Ob = O  + (size_t)b * L_ * D_;
  const _Float16* Pb = (const _Float16*)Ob;
  __shared__ __align__(16) _Float16 Bs[32768];
  const int t = threadIdx.x, lane = t & 63, w = t >> 6;
  f32x4 acc[4][8];
  { f32x4 z = {0,0,0,0};
    #pragma unroll
    for (int i = 0; i < 4; ++i)
      #pragma unroll
      for (int j = 0; j < 8; ++j) acc[i][j] = z; }
  for (int kt = 0; kt < 32; ++kt) {
    const int v0 = kt * 32;
    #pragma unroll
    for (int i = 0; i < 8; ++i) {
      const int c = t + i * 512, kg = c >> 10, d = c & 1023;
      const float* src = Vb + (size_t)(v0 + kg * 8) * D_ + d;
      f32x4 x0, x1;
      x0[0] = src[0*D_]; x0[1] = src[1*D_]; x0[2] = src[2*D_]; x0[3] = src[3*D_];
      x1[0] = src[4*D_]; x1[1] = src[5*D_]; x1[2] = src[6*D_]; x1[3] = src[7*D_];
      *(half8_t*)&Bs[(kg * 1024 + d) * 8] = cvt8(x0, x1);
    }
    __syncthreads();
    const int fkg = lane >> 4, fr = lane & 15;
    half8_t af[4];
    #pragma unroll
    for (int mt = 0; mt < 4; ++mt)
      af[mt] = *(const half8_t*)(Pb + (size_t)(r0 + mt * 16 + fr) * 2048 + v0 + fkg * 8);
    #pragma unroll
    for (int nt = 0; nt < 8; ++nt) {
      half8_t bf = *(const half8_t*)&Bs[(fkg * 1024 + w * 128 + nt * 16 + fr) * 8];
      #pragma unroll
      for (int mt = 0; mt < 4; ++mt)
        acc[mt][nt] = __builtin_amdgcn_mfma_f32_16x16x32_f16(af[mt], bf, acc[mt][nt], 0, 0, 0);
    }
    __syncthreads();
  }
  const int rq = (lane >> 4) * 4;
  #pragma unroll
  for (int mt = 0; mt < 4; ++mt)
    #pragma unroll
    for (int nt = 0; nt < 8; ++nt) {
      const int col = w * 128 + nt * 16 + (lane & 15);
      const int rb  = r0 + mt * 16 + rq;
      #pragma unroll
      for (int r = 0; r < 4; ++r) Ob[(size_t)(rb + r) * D_ + col] = acc[mt][nt][r];
    }
}

extern "C" void kernel_launch(void* const* d_in, const int* in_sizes, int n_in,
                              void* d_out, int out_size, void* d_ws, size_t ws_size,
                              hipStream_t stream) {
  (void)in_sizes; (void)n_in; (void)out_size;
  const float* H  = (const float*)d_in[0];   // (8, 2048, 1024)
  const float* Vv = (const float*)d_in[1];   // (8, 1024, 1024)
  float* O = (float*)d_out;                  // (8, 2048, 1024)

  const size_t need = (size_t)64 * 1024 * 1024;  // Hh/P 32M + Vh 16M + VTh 16M
  if (ws_size >= need && d_ws != nullptr) {
    _Float16* Hh  = (_Float16*)d_ws;            // 32 MB; becomes P after G1
    _Float16* Vh  = Hh + (size_t)B_ * L_ * D_;  // 16 MB
    _Float16* VTh = Vh + (size_t)B_ * V_ * D_;  // 16 MB
    _Float16* P   = Hh;                         // reuse (Hh dead after G1)

    p0_hconv<<<dim3((B_ * L_ * D_) / (256 * 8)), 256, 0, stream>>>(H, Hh);
    p1_vconv<<<dim3(D_ / 64, V_ / 64, B_), 256, 0, stream>>>(Vv, Vh, VTh);
    // S = Hh @ Vh^T  -> d_out
    gemm_bt16<<<dim3(V_ / 128, L_ / 128, B_), 256, 0, stream>>>(
        Hh, Vh, O, (long)D_, (long)L_ * D_, (long)V_ * D_, (long)L_ * V_);
    // P = softmax(S) -> ws (fp16, dense); 1 wave/row
    k2_softmax<<<dim3(B_ * L_ / 4), 256, 0, stream>>>(O, P);
    // O = P @ VTh^T  -> d_out (A,B both in ws: no aliasing with C)
    gemm_bt16<<<dim3(D_ / 128, L_ / 128, B_), 256, 0, stream>>>(
        P, VTh, O, (long)V_, (long)L_ * V_, (long)D_ * V_, (long)L_ * D_);
  } else {
    k1_slow<<<dim3(V_ / 128, L_ / 128, B_), 256, 0, stream>>>(H, Vv, O);
    k2_slow<<<dim3(B_ * L_), 256, 0, stream>>>(O);
    k3_slow<<<dim3(L_ / 64, B_), 512, 0, stream>>>(Vv, O);
  }
}